// Round 1
// baseline (141.475 us; speedup 1.0000x reference)
//
#include <hip/hip_runtime.h>

// ESRNN Holt-Winters: B=8192 series, T=1024 steps, P=12 seasonal period.
// One thread per series; seasonal ring in 12 registers via 12-step unroll.
// 1024 = 85*12 + 4 tail. Ring invariant: front at step t is s[t % 12];
// c written at t is re-read as front at t+12 (same slot); output factor
// s_new[0] = slot (t+1)%12 (already holds the value written at t-11).

#define T_STEPS 1024

__global__ __launch_bounds__(64) void esrnn_kernel(
    const float* __restrict__ y, const float* __restrict__ l0,
    const float* __restrict__ b0, const float* __restrict__ s0,
    const float* __restrict__ alpha_p, const float* __restrict__ beta_p,
    const float* __restrict__ phi_p, const float* __restrict__ gamma_p,
    float* __restrict__ out)
{
    const int b = blockIdx.x * 64 + threadIdx.x;

    const float alpha = alpha_p[0];
    const float beta  = beta_p[0];
    const float phi   = phi_p[0];
    const float gamma = gamma_p[0];
    const float oma    = 1.0f - alpha;
    const float omg    = 1.0f - gamma;
    const float ombphi = (1.0f - beta) * phi;

    float l  = l0[b];
    float bt = b0[b];
    float s[12];
#pragma unroll
    for (int k = 0; k < 12; ++k) s[k] = s0[b * 12 + k];

    const float* yb = y   + (size_t)b * T_STEPS;
    float*       ob = out + (size_t)b * T_STEPS;

    // Prefetched y registers for the current 12-step window.
    float4 f0 = *(const float4*)(yb + 0);
    float4 f1 = *(const float4*)(yb + 4);
    float4 f2 = *(const float4*)(yb + 8);

    for (int i = 0; i < 85; ++i) {
        const int t0 = 12 * i;
        // Prefetch next window (tail window for the last iteration).
        float4 n0, n1, n2;
        if (i < 84) {
            n0 = *(const float4*)(yb + t0 + 12);
            n1 = *(const float4*)(yb + t0 + 16);
            n2 = *(const float4*)(yb + t0 + 20);
        } else {
            n0 = *(const float4*)(yb + 1020);  // tail 4 values
            n1 = n0; n2 = n0;
        }

        const float yv[12] = {f0.x, f0.y, f0.z, f0.w,
                              f1.x, f1.y, f1.z, f1.w,
                              f2.x, f2.y, f2.z, f2.w};
        float o[12];
#pragma unroll
        for (int j = 0; j < 12; ++j) {
            const float yt = yv[j];
            const float sf = s[j];                          // front = s[t%12]
            const float rs = __builtin_amdgcn_rcpf(sf);
            const float a  = alpha * yt * rs;               // alpha*y/s_front
            const float ln = fmaf(oma, fmaf(phi, bt, l), a);
            const float bn = fmaf(beta, ln - l, ombphi * bt);
            const float rl = __builtin_amdgcn_rcpf(ln);
            const float c  = fmaf(gamma * yt, rl, omg * sf);
            s[j] = c;
            // next front: slot (j+1)%12. For j==11 this is s[0], which was
            // correctly rewritten at j==0 of THIS window (t-11).
            const float snext = (j < 11) ? s[j + 1] : s[0];
            o[j] = fmaf(phi, bn, ln) * snext;
            l = ln; bt = bn;
        }

        *(float4*)(ob + t0 + 0) = make_float4(o[0], o[1], o[2],  o[3]);
        *(float4*)(ob + t0 + 4) = make_float4(o[4], o[5], o[6],  o[7]);
        *(float4*)(ob + t0 + 8) = make_float4(o[8], o[9], o[10], o[11]);

        f0 = n0; f1 = n1; f2 = n2;
    }

    // Tail: t = 1020..1023, ring offset 0 (1020 % 12 == 0).
    {
        const float yv[4] = {f0.x, f0.y, f0.z, f0.w};
        float o[4];
#pragma unroll
        for (int j = 0; j < 4; ++j) {
            const float yt = yv[j];
            const float sf = s[j];
            const float rs = __builtin_amdgcn_rcpf(sf);
            const float a  = alpha * yt * rs;
            const float ln = fmaf(oma, fmaf(phi, bt, l), a);
            const float bn = fmaf(beta, ln - l, ombphi * bt);
            const float rl = __builtin_amdgcn_rcpf(ln);
            const float c  = fmaf(gamma * yt, rl, omg * sf);
            s[j] = c;
            o[j] = fmaf(phi, bn, ln) * s[j + 1];   // j+1 <= 4, untouched slots
            l = ln; bt = bn;
        }
        *(float4*)(ob + 1020) = make_float4(o[0], o[1], o[2], o[3]);
    }
}

extern "C" void kernel_launch(void* const* d_in, const int* in_sizes, int n_in,
                              void* d_out, int out_size, void* d_ws, size_t ws_size,
                              hipStream_t stream) {
    const float* y     = (const float*)d_in[0];
    const float* l0    = (const float*)d_in[1];
    const float* b0    = (const float*)d_in[2];
    const float* s0    = (const float*)d_in[3];
    const float* alpha = (const float*)d_in[4];
    const float* beta  = (const float*)d_in[5];
    const float* phi   = (const float*)d_in[6];
    const float* gamma = (const float*)d_in[7];
    float* out = (float*)d_out;

    // 8192 series / 64 threads = 128 blocks -> 1 wave on each of 128 CUs.
    esrnn_kernel<<<dim3(128), dim3(64), 0, stream>>>(
        y, l0, b0, s0, alpha, beta, phi, gamma, out);
}

// Round 2
// 127.033 us; speedup vs baseline: 1.1137x; 1.1137x over previous
//
#include <hip/hip_runtime.h>

// ESRNN Holt-Winters: B=8192, T=1024, P=12.
// 1 thread/series, 64 series/block (1 wave), 128 blocks -> 1 wave/CU on 128 CUs.
// Structural latency hiding: y staged global->LDS via global_load_lds in
// 64-timestep chunks, double-buffered; sync-then-issue ordering guarantees
// ~1900 cyc of slack per chunk vs ~900 cyc HBM latency.
// LDS layout: series-stride 65 words -> read bank = (lane + t) % 32 = 2-way (free).
// Seasonal ring in 12 registers; 12-step windows; 192-step super-pattern
// (LCM(12,64)) with crossing windows w5 (t 60..71) and w10 (t 120..131).

#define LS 65           // padded per-series stride in LDS (words)
#define BW (64 * LS)    // one buffer: 64 series * 65 words = 4160 words

typedef __attribute__((address_space(1))) const void* as1cv;
typedef __attribute__((address_space(3))) void* as3v;

// Stage chunk c (timesteps [64c, 64c+64) of all 64 series) into dst buffer.
// One instruction per series: lanes load 64 contiguous floats (256 B coalesced),
// land at dst + r*LS + lane (wave-uniform base + lane*4 semantics).
__device__ __forceinline__ void stage_chunk(const float* yg, int c, float* dst,
                                            int lane) {
    const float* g = yg + c * 64 + lane;
#pragma unroll
    for (int r = 0; r < 64; ++r) {
        __builtin_amdgcn_global_load_lds((as1cv)(g + r * 1024),
                                         (as3v)(dst + r * LS), 4, 0, 0);
    }
}

// One 12-step window: consumes yv[12], updates l/bt/s ring, stores 12 outputs
// as 3 float4 to op. Window always starts at ring slot 0 (t % 12 == 0).
__device__ __forceinline__ void window_compute(
    const float* yv, float& l, float& bt, float* s,
    float alpha, float oma, float beta, float ombphi,
    float gamma, float omg, float phi, float* op)
{
    float o[12];
#pragma unroll
    for (int j = 0; j < 12; ++j) {
        const float yt = yv[j];
        const float sf = s[j];
        const float rs = __builtin_amdgcn_rcpf(sf);
        const float a  = alpha * yt * rs;
        const float ln = fmaf(oma, fmaf(phi, bt, l), a);
        const float bn = fmaf(beta, ln - l, ombphi * bt);
        const float rl = __builtin_amdgcn_rcpf(ln);
        const float c  = fmaf(gamma * yt, rl, omg * sf);
        s[j] = c;
        const float sn = (j < 11) ? s[j + 1] : s[0];
        o[j] = fmaf(phi, bn, ln) * sn;
        l = ln; bt = bn;
    }
    *(float4*)(op + 0) = make_float4(o[0], o[1], o[2],  o[3]);
    *(float4*)(op + 4) = make_float4(o[4], o[5], o[6],  o[7]);
    *(float4*)(op + 8) = make_float4(o[8], o[9], o[10], o[11]);
}

__global__ __launch_bounds__(64) void esrnn_kernel(
    const float* __restrict__ y, const float* __restrict__ l0,
    const float* __restrict__ b0, const float* __restrict__ s0,
    const float* __restrict__ alpha_p, const float* __restrict__ beta_p,
    const float* __restrict__ phi_p, const float* __restrict__ gamma_p,
    float* __restrict__ out)
{
    __shared__ float ybuf[2 * BW];   // 33,280 B

    const int lane = threadIdx.x;
    const int b = blockIdx.x * 64 + lane;
    const float* yg = y + (size_t)blockIdx.x * 64 * 1024;

    const float alpha = alpha_p[0];
    const float beta  = beta_p[0];
    const float phi   = phi_p[0];
    const float gamma = gamma_p[0];
    const float oma    = 1.0f - alpha;
    const float omg    = 1.0f - gamma;
    const float ombphi = (1.0f - beta) * phi;

    // Prologue: chunk 0 -> buf0 (parity 0), overlapped with state loads below.
    stage_chunk(yg, 0, ybuf, lane);

    float l  = l0[b];
    float bt = b0[b];
    float s[12];
#pragma unroll
    for (int i = 0; i < 12; ++i) s[i] = s0[b * 12 + i];

    float* ob = out + (size_t)b * 1024;

    const float* pb0 = ybuf + lane * LS;
    const float* pb1 = ybuf + BW + lane * LS;

    for (int k = 0; k < 5; ++k) {
        const int p = k & 1;
        // pe: buffer holding even-offset chunks this iter (A=3k, then C=3k+2)
        // po: buffer holding the odd chunk B=3k+1
        const float* pe = p ? pb1 : pb0;
        const float* po = p ? pb0 : pb1;
        float* de = ybuf + (size_t)p * BW;          // stage dest, parity p
        float* dq = ybuf + (size_t)(p ^ 1) * BW;    // stage dest, parity p^1
        float* op = ob + k * 192;

        // Wait for chunk A (issued last iter / prologue), THEN issue chunk B.
        __syncthreads();
        stage_chunk(yg, 3 * k + 1, dq, lane);

        // w0..w4: t = 0..59, chunk A in pe
#pragma unroll
        for (int w = 0; w < 5; ++w) {
            float yv[12];
#pragma unroll
            for (int j = 0; j < 12; ++j) yv[j] = pe[w * 12 + j];
            window_compute(yv, l, bt, s, alpha, oma, beta, ombphi,
                           gamma, omg, phi, op + w * 12);
        }

        // Wait for chunk B before w5 touches it.
        __syncthreads();
        {   // w5 crossing: t 60..63 from A (pe), t 64..71 from B (po)
            float yv[12];
#pragma unroll
            for (int j = 0; j < 4; ++j)  yv[j] = pe[60 + j];
#pragma unroll
            for (int j = 4; j < 12; ++j) yv[j] = po[j - 4];
            window_compute(yv, l, bt, s, alpha, oma, beta, ombphi,
                           gamma, omg, phi, op + 60);
        }
        // Chunk A now dead -> stage chunk C=3k+2 over it.
        stage_chunk(yg, 3 * k + 2, de, lane);

        // w6..w9: t = 72..119, chunk B: po[8..55]
#pragma unroll
        for (int w = 6; w < 10; ++w) {
            float yv[12];
#pragma unroll
            for (int j = 0; j < 12; ++j) yv[j] = po[w * 12 - 64 + j];
            window_compute(yv, l, bt, s, alpha, oma, beta, ombphi,
                           gamma, omg, phi, op + w * 12);
        }

        // Wait for chunk C before w10 touches it.
        __syncthreads();
        {   // w10 crossing: t 120..127 from B (po[56..63]), t 128..131 from C (pe[0..3])
            float yv[12];
#pragma unroll
            for (int j = 0; j < 8; ++j)  yv[j] = po[56 + j];
#pragma unroll
            for (int j = 8; j < 12; ++j) yv[j] = pe[j - 8];
            window_compute(yv, l, bt, s, alpha, oma, beta, ombphi,
                           gamma, omg, phi, op + 120);
        }
        // Chunk B dead -> stage next A = 3k+3 (k=4 stages the tail chunk 15).
        stage_chunk(yg, 3 * k + 3, dq, lane);

        // w11..w15: t = 132..191, chunk C: pe[4..63]
#pragma unroll
        for (int w = 11; w < 16; ++w) {
            float yv[12];
#pragma unroll
            for (int j = 0; j < 12; ++j) yv[j] = pe[w * 12 - 128 + j];
            window_compute(yv, l, bt, s, alpha, oma, beta, ombphi,
                           gamma, omg, phi, op + w * 12);
        }
    }

    // Tail: chunk 15 (t 960..1023) is in buf1 (parity 15&1 == 1).
    __syncthreads();
    {
        const float* pt = pb1;
        float* op = ob + 960;
#pragma unroll
        for (int w = 0; w < 5; ++w) {
            float yv[12];
#pragma unroll
            for (int j = 0; j < 12; ++j) yv[j] = pt[w * 12 + j];
            window_compute(yv, l, bt, s, alpha, oma, beta, ombphi,
                           gamma, omg, phi, op + w * 12);
        }
        // Final 4 steps: t 1020..1023 (ring slots 0..3).
        float o[4];
#pragma unroll
        for (int j = 0; j < 4; ++j) {
            const float yt = pt[60 + j];
            const float sf = s[j];
            const float rs = __builtin_amdgcn_rcpf(sf);
            const float a  = alpha * yt * rs;
            const float ln = fmaf(oma, fmaf(phi, bt, l), a);
            const float bn = fmaf(beta, ln - l, ombphi * bt);
            const float rl = __builtin_amdgcn_rcpf(ln);
            const float c  = fmaf(gamma * yt, rl, omg * sf);
            s[j] = c;
            o[j] = fmaf(phi, bn, ln) * s[j + 1];
            l = ln; bt = bn;
        }
        *(float4*)(op + 60) = make_float4(o[0], o[1], o[2], o[3]);
    }
}

extern "C" void kernel_launch(void* const* d_in, const int* in_sizes, int n_in,
                              void* d_out, int out_size, void* d_ws, size_t ws_size,
                              hipStream_t stream) {
    const float* y     = (const float*)d_in[0];
    const float* l0    = (const float*)d_in[1];
    const float* b0    = (const float*)d_in[2];
    const float* s0    = (const float*)d_in[3];
    const float* alpha = (const float*)d_in[4];
    const float* beta  = (const float*)d_in[5];
    const float* phi   = (const float*)d_in[6];
    const float* gamma = (const float*)d_in[7];
    float* out = (float*)d_out;

    esrnn_kernel<<<dim3(128), dim3(64), 0, stream>>>(
        y, l0, b0, s0, alpha, beta, phi, gamma, out);
}

// Round 3
// 122.690 us; speedup vs baseline: 1.1531x; 1.0354x over previous
//
#include <hip/hip_runtime.h>

// ESRNN Holt-Winters: B=8192, T=1024, P=12.
// Wave-specialized: block = 256 threads (4 waves), 128 blocks, ~1 block/CU.
//   wave 0   : compute, 1 series/lane. Reads y from LDS, writes o to LDS.
//              NO global/vmem ops in steady state -> barrier waits are lgkmcnt-cheap.
//   wave 1   : y stager. global_load_lds 64-step chunks, double buffered.
//              Its s_waitcnt vmcnt(0) drain overlaps wave 0's compute.
//   waves 2-3: output writeback. LDS -> coalesced 256B global stores; absorb
//              store-retire latency.
// Pipeline (phase n): stage chunk n | compute chunk n-1 | store chunk n-2.
// 16 chunks -> 18 phases, one __syncthreads per phase.
// LDS: y dbuf 2*64*65 words + o dbuf 2*64*65 words = 66,560 B.
// All LDS access patterns have bank = (lane + const) % 32 -> 2-way (free).
// Seasonal ring s[12] + reciprocal ring rs[12] in registers; chunk start ring
// offset R = (64c) % 12 cycles {0,4,8} -> 3 static code variants.
// Divisions: 1-step Newton from previous reciprocal (rl: seed err ~4% ->
// 1.8e-3 rel; rs: seed err ~0.5% -> ~1e-5 rel) instead of v_rcp (8 cyc issue).

#define LSY 65
#define YBW (64 * LSY)
#define LSO 65
#define OBW (64 * LSO)

typedef __attribute__((address_space(1))) const void* as1cv;
typedef __attribute__((address_space(3))) void* as3v;

// One ES step. IDX: step index within chunk (y LDS offset, o LDS offset/LSO).
// J: ring slot = (R + IDX) % 12, compile-time.
#define ES_STEP(IDX, J)                                                \
  {                                                                    \
    constexpr int _J  = (J);                                           \
    constexpr int _Jn = ((J) + 1) % 12;                                \
    const float yt = yb[(IDX)];                                        \
    const float a  = (alpha * yt) * rs[_J];                            \
    const float ln = fmaf(oma, pn, a);                                 \
    const float inner = fmaf(nbeta, l, ombphi * bt);                   \
    const float bn  = fmaf(beta, ln, inner);                           \
    const float pnn = fmaf(phi, bn, ln);                               \
    rl = rl * fmaf(-ln, rl, 2.0f);            /* Newton: rl ~= 1/ln */ \
    const float sf = s[_J];                                            \
    const float c  = fmaf(gamma * yt, rl, omg * sf);                   \
    s[_J] = c;                                                         \
    rs[_J] = rs[_J] * fmaf(-c, rs[_J], 2.0f); /* Newton: rs ~= 1/c  */ \
    ob[(IDX) * LSO] = pnn * s[_Jn];                                    \
    l = ln; bt = bn; pn = pnn;                                         \
  }

#define ES_W12(B)                                                      \
  ES_STEP((B) + 0, 0)  ES_STEP((B) + 1, 1)  ES_STEP((B) + 2, 2)        \
  ES_STEP((B) + 3, 3)  ES_STEP((B) + 4, 4)  ES_STEP((B) + 5, 5)        \
  ES_STEP((B) + 6, 6)  ES_STEP((B) + 7, 7)  ES_STEP((B) + 8, 8)        \
  ES_STEP((B) + 9, 9)  ES_STEP((B) + 10, 10) ES_STEP((B) + 11, 11)

__global__ __launch_bounds__(256) void esrnn_kernel(
    const float* __restrict__ y, const float* __restrict__ l0,
    const float* __restrict__ b0, const float* __restrict__ s0,
    const float* __restrict__ alpha_p, const float* __restrict__ beta_p,
    const float* __restrict__ phi_p, const float* __restrict__ gamma_p,
    float* __restrict__ out)
{
    __shared__ float ybuf[2 * YBW];
    __shared__ float obuf[2 * OBW];

    const int tid  = threadIdx.x;
    const int wid  = tid >> 6;
    const int lane = tid & 63;

    const float alpha = alpha_p[0];
    const float beta  = beta_p[0];
    const float phi   = phi_p[0];
    const float gamma = gamma_p[0];
    const float oma    = 1.0f - alpha;
    const float omg    = 1.0f - gamma;
    const float nbeta  = -beta;
    const float ombphi = (1.0f - beta) * phi;

    const float* yg = y + (size_t)blockIdx.x * 64 * 1024;

    // Compute-wave state (wave 0 only; dead regs elsewhere).
    float l = 1.0f, bt = 0.0f, pn = 1.0f, rl = 1.0f;
    float s[12], rs[12];
#pragma unroll
    for (int k = 0; k < 12; ++k) { s[k] = 1.0f; rs[k] = 1.0f; }

    if (wid == 0) {
        const int b = blockIdx.x * 64 + lane;
        l  = l0[b];
        bt = b0[b];
        const float4 s03 = *(const float4*)(s0 + b * 12);
        const float4 s47 = *(const float4*)(s0 + b * 12 + 4);
        const float4 s8b = *(const float4*)(s0 + b * 12 + 8);
        s[0] = s03.x; s[1] = s03.y; s[2]  = s03.z; s[3]  = s03.w;
        s[4] = s47.x; s[5] = s47.y; s[6]  = s47.z; s[7]  = s47.w;
        s[8] = s8b.x; s[9] = s8b.y; s[10] = s8b.z; s[11] = s8b.w;
#pragma unroll
        for (int k = 0; k < 12; ++k) rs[k] = __builtin_amdgcn_rcpf(s[k]);
        rl = __builtin_amdgcn_rcpf(l);
        pn = fmaf(phi, bt, l);
    }

    for (int n = 0; n < 18; ++n) {
        if (wid == 1) {
            // ---- stager: chunk n -> ybuf[n&1] ----
            if (n <= 15) {
                const float* g = yg + n * 64 + lane;
                float* dst = ybuf + (size_t)(n & 1) * YBW;
#pragma unroll
                for (int r = 0; r < 64; ++r) {
                    __builtin_amdgcn_global_load_lds((as1cv)(g + r * 1024),
                                                     (as3v)(dst + r * LSY),
                                                     4, 0, 0);
                }
            }
        } else if (wid == 0) {
            // ---- compute: chunk c = n-1 from ybuf[c&1], o -> obuf[c&1] ----
            if (n >= 1 && n <= 16) {
                const int c = n - 1;
                const float* yb = ybuf + (size_t)(c & 1) * YBW + lane * LSY;
                float*       ob = obuf + (size_t)(c & 1) * OBW + lane;
                const int m = c % 3;   // ring offset R = {0,4,8}
                if (m == 0) {
                    for (int w = 0; w < 5; ++w) { const int B = w * 12; ES_W12(B) }
                    ES_STEP(60, 0) ES_STEP(61, 1) ES_STEP(62, 2) ES_STEP(63, 3)
                } else if (m == 1) {
                    ES_STEP(0, 4) ES_STEP(1, 5) ES_STEP(2, 6)  ES_STEP(3, 7)
                    ES_STEP(4, 8) ES_STEP(5, 9) ES_STEP(6, 10) ES_STEP(7, 11)
                    for (int w = 0; w < 4; ++w) { const int B = 8 + w * 12; ES_W12(B) }
                    ES_STEP(56, 0) ES_STEP(57, 1) ES_STEP(58, 2) ES_STEP(59, 3)
                    ES_STEP(60, 4) ES_STEP(61, 5) ES_STEP(62, 6) ES_STEP(63, 7)
                } else {
                    ES_STEP(0, 8) ES_STEP(1, 9) ES_STEP(2, 10) ES_STEP(3, 11)
                    for (int w = 0; w < 5; ++w) { const int B = 4 + w * 12; ES_W12(B) }
                }
            }
        } else {
            // ---- storer (waves 2,3): chunk c = n-2 from obuf[c&1] ----
            if (n >= 2) {
                const int c = n - 2;
                const int sbase = (wid - 2) * 32;
                const float* obr = obuf + (size_t)(c & 1) * OBW + lane * LSO + sbase;
                float* og = out + (size_t)(blockIdx.x * 64 + sbase) * 1024
                                + c * 64 + lane;
#pragma unroll
                for (int r = 0; r < 32; ++r) {
                    og[(size_t)r * 1024] = obr[r];
                }
            }
        }
        __syncthreads();
    }
}

extern "C" void kernel_launch(void* const* d_in, const int* in_sizes, int n_in,
                              void* d_out, int out_size, void* d_ws, size_t ws_size,
                              hipStream_t stream) {
    const float* y     = (const float*)d_in[0];
    const float* l0    = (const float*)d_in[1];
    const float* b0    = (const float*)d_in[2];
    const float* s0    = (const float*)d_in[3];
    const float* alpha = (const float*)d_in[4];
    const float* beta  = (const float*)d_in[5];
    const float* phi   = (const float*)d_in[6];
    const float* gamma = (const float*)d_in[7];
    float* out = (float*)d_out;

    esrnn_kernel<<<dim3(128), dim3(256), 0, stream>>>(
        y, l0, b0, s0, alpha, beta, phi, gamma, out);
}

// Round 4
// 121.017 us; speedup vs baseline: 1.1690x; 1.0138x over previous
//
#include <hip/hip_runtime.h>

// ESRNN Holt-Winters: B=8192, T=1024, P=12.
// Wave-specialized: block = 256 threads (4 waves), 128 blocks, 1 block/CU.
//   wave 0   : compute, 1 series/lane. Batched LDS access: 16 ds_reads ->
//              16 pure-VALU steps -> 16 ds_writes. No vmem ops ever.
//   wave 1   : y stager (global_load_lds, 64-step chunks, double buffered).
//   waves 2-3: output writeback (LDS -> coalesced 256B global stores).
// Pipeline (phase n): stage chunk n | compute chunk n-1 | store chunk n-2.
// LDS: y dbuf 2*64*65 + o dbuf 2*64*65 words = 66,560 B. All LDS patterns
// bank = (lane + const) % 32 -> 2-way (free on CDNA4).
// Seasonal ring s[12] + reciprocal ring rs[12] in registers; all indices
// compile-time via template<int R> batches (R = ring offset, cycles {0,4,8}).
// Divisions replaced by 1-step Newton from previous reciprocal:
//   rl ~= 1/l  (seed drift ~2%/step  -> rel err ~4e-4, feeds gamma-term only)
//   rs ~= 1/s  (seed drift ~0.5%/12s -> rel err ~1e-5)
// absmax impact << 8.4e-2 threshold (measured 0.0156 in rounds 2-3).

#define LSY 65
#define YBW (64 * LSY)
#define LSO 65
#define OBW (64 * LSO)

typedef __attribute__((address_space(1))) const void* as1cv;
typedef __attribute__((address_space(3))) void* as3v;

// 16 ES steps starting at ring offset R (compile-time), chunk-local step
// index base..base+15. yb/ob are lane-resolved LDS pointers.
template<int R>
__device__ __forceinline__ void batch16(
    const float* yb, float* ob, int base,
    float& l, float& bt, float& pn, float& rl, float* s, float* rs,
    float alpha, float oma, float beta, float nbeta, float ombphi,
    float gamma, float omg, float phi)
{
    float yv[16];
#pragma unroll
    for (int i = 0; i < 16; ++i) yv[i] = yb[base + i];

    float ov[16];
#pragma unroll
    for (int i = 0; i < 16; ++i) {
        const int J  = (R + i) % 12;      // constant after unroll
        const int Jn = (R + i + 1) % 12;
        const float yt = yv[i];
        const float ay = alpha * yt;
        const float a  = ay * rs[J];
        const float ln = fmaf(oma, pn, a);
        const float inner = fmaf(nbeta, l, ombphi * bt);
        const float bn  = fmaf(beta, ln, inner);
        const float pnn = fmaf(phi, bn, ln);
        rl = rl * fmaf(-ln, rl, 2.0f);          // Newton: rl ~= 1/ln
        const float gy = gamma * yt;
        const float c  = fmaf(gy, rl, omg * s[J]);
        s[J] = c;
        rs[J] = rs[J] * fmaf(-c, rs[J], 2.0f);  // Newton: rs ~= 1/c
        ov[i] = pnn * s[Jn];
        l = ln; bt = bn; pn = pnn;
    }

#pragma unroll
    for (int i = 0; i < 16; ++i) ob[(base + i) * LSO] = ov[i];
}

#define BATCH_ARGS l, bt, pn, rl, s, rs, alpha, oma, beta, nbeta, ombphi, gamma, omg, phi

__global__ __launch_bounds__(256) void esrnn_kernel(
    const float* __restrict__ y, const float* __restrict__ l0,
    const float* __restrict__ b0, const float* __restrict__ s0,
    const float* __restrict__ alpha_p, const float* __restrict__ beta_p,
    const float* __restrict__ phi_p, const float* __restrict__ gamma_p,
    float* __restrict__ out)
{
    __shared__ float ybuf[2 * YBW];
    __shared__ float obuf[2 * OBW];

    const int tid  = threadIdx.x;
    const int wid  = tid >> 6;
    const int lane = tid & 63;

    const float alpha = alpha_p[0];
    const float beta  = beta_p[0];
    const float phi   = phi_p[0];
    const float gamma = gamma_p[0];
    const float oma    = 1.0f - alpha;
    const float omg    = 1.0f - gamma;
    const float nbeta  = -beta;
    const float ombphi = (1.0f - beta) * phi;

    const float* yg = y + (size_t)blockIdx.x * 64 * 1024;

    // Compute-wave state (dead regs in other waves).
    float l = 1.0f, bt = 0.0f, pn = 1.0f, rl = 1.0f;
    float s[12], rs[12];
#pragma unroll
    for (int k = 0; k < 12; ++k) { s[k] = 1.0f; rs[k] = 1.0f; }

    if (wid == 0) {
        const int b = blockIdx.x * 64 + lane;
        l  = l0[b];
        bt = b0[b];
        const float4 s03 = *(const float4*)(s0 + b * 12);
        const float4 s47 = *(const float4*)(s0 + b * 12 + 4);
        const float4 s8b = *(const float4*)(s0 + b * 12 + 8);
        s[0] = s03.x; s[1] = s03.y; s[2]  = s03.z; s[3]  = s03.w;
        s[4] = s47.x; s[5] = s47.y; s[6]  = s47.z; s[7]  = s47.w;
        s[8] = s8b.x; s[9] = s8b.y; s[10] = s8b.z; s[11] = s8b.w;
#pragma unroll
        for (int k = 0; k < 12; ++k) rs[k] = __builtin_amdgcn_rcpf(s[k]);
        rl = __builtin_amdgcn_rcpf(l);
        pn = fmaf(phi, bt, l);
    }

    for (int n = 0; n < 18; ++n) {
        if (wid == 1) {
            // ---- stager: chunk n -> ybuf[n&1] ----
            if (n <= 15) {
                const float* g = yg + n * 64 + lane;
                float* dst = ybuf + (size_t)(n & 1) * YBW;
#pragma unroll
                for (int r = 0; r < 64; ++r) {
                    __builtin_amdgcn_global_load_lds((as1cv)(g + r * 1024),
                                                     (as3v)(dst + r * LSY),
                                                     4, 0, 0);
                }
            }
        } else if (wid == 0) {
            // ---- compute: chunk c = n-1 from ybuf[c&1], o -> obuf[c&1] ----
            if (n >= 1 && n <= 16) {
                const int c = n - 1;
                const float* yb = ybuf + (size_t)(c & 1) * YBW + lane * LSY;
                float*       ob = obuf + (size_t)(c & 1) * OBW + lane;
                const int m = c % 3;   // chunk ring offset R0 = {0,4,8}
                if (m == 0) {
                    batch16<0>(yb, ob, 0,  BATCH_ARGS);
                    batch16<4>(yb, ob, 16, BATCH_ARGS);
                    batch16<8>(yb, ob, 32, BATCH_ARGS);
                    batch16<0>(yb, ob, 48, BATCH_ARGS);
                } else if (m == 1) {
                    batch16<4>(yb, ob, 0,  BATCH_ARGS);
                    batch16<8>(yb, ob, 16, BATCH_ARGS);
                    batch16<0>(yb, ob, 32, BATCH_ARGS);
                    batch16<4>(yb, ob, 48, BATCH_ARGS);
                } else {
                    batch16<8>(yb, ob, 0,  BATCH_ARGS);
                    batch16<0>(yb, ob, 16, BATCH_ARGS);
                    batch16<4>(yb, ob, 32, BATCH_ARGS);
                    batch16<8>(yb, ob, 48, BATCH_ARGS);
                }
            }
        } else {
            // ---- storer (waves 2,3): chunk c = n-2 from obuf[c&1] ----
            if (n >= 2) {
                const int c = n - 2;
                const int sbase = (wid - 2) * 32;
                const float* obr = obuf + (size_t)(c & 1) * OBW + lane * LSO + sbase;
                float* og = out + (size_t)(blockIdx.x * 64 + sbase) * 1024
                                + c * 64 + lane;
#pragma unroll
                for (int r = 0; r < 32; ++r) {
                    og[(size_t)r * 1024] = obr[r];
                }
            }
        }
        __syncthreads();
    }
}

extern "C" void kernel_launch(void* const* d_in, const int* in_sizes, int n_in,
                              void* d_out, int out_size, void* d_ws, size_t ws_size,
                              hipStream_t stream) {
    const float* y     = (const float*)d_in[0];
    const float* l0    = (const float*)d_in[1];
    const float* b0    = (const float*)d_in[2];
    const float* s0    = (const float*)d_in[3];
    const float* alpha = (const float*)d_in[4];
    const float* beta  = (const float*)d_in[5];
    const float* phi   = (const float*)d_in[6];
    const float* gamma = (const float*)d_in[7];
    float* out = (float*)d_out;

    esrnn_kernel<<<dim3(128), dim3(256), 0, stream>>>(
        y, l0, b0, s0, alpha, beta, phi, gamma, out);
}